// Round 7
// baseline (1794.298 us; speedup 1.0000x reference)
//
#include <hip/hip_runtime.h>

// ---------------------------------------------------------------------------
// GCN: 4 layers of  h' = A_hat_norm (h @ W) + b   on fixed graph, fp32.
// g = (h@W) * dinv[row]  (GEMM epilogue), then per-dst:
//   h'[dst] = dinv[dst] * ( g[dst] + sum_{src in N(dst)} g[src] ) + b
// R2: gemm spill fixed. R3: CSR fill via binned counting sort.
// R4: per-node degree/scan/fill all in LDS per 256-node bin.
// R5: feature-chunked G [8][N][8]: agg L2-miss 362->77MB but latency-bound.
// R6: slot-shaped agg (8 nodes x 8 feats/wave) -- blockIdx&7 XCD-affinity
// drifted with long blocks; FETCH back to 257MB (L2 thrash).
// R7: TRUE XCD pinning: each block reads HW_REG_XCC_ID and pulls 128-node
// grains of its own XCD's chunk from a per-chunk atomic cursor; after own
// chunk drains it steals (xcd+off)&7 -- correct under any dispatch. Slot
// shape kept, 4 gather chains per slot for latency hiding.
// ---------------------------------------------------------------------------

#define FEAT 128
#define EMB 64
#define BINSHIFT 8
#define BINSIZE 256
#define NBIN 391          // ceil(100000/256)
#define CHUNK 8192
#define GRAIN 128         // nodes per work grain (4 waves x 32 nodes)

// ---------------- CSR build ----------------

__global__ void zero_k(int* __restrict__ p, int n) {
    int i = blockIdx.x * blockDim.x + threadIdx.x;
    if (i < n) p[i] = 0;
}

// Pass A: per-bin edge counts. LDS histogram per chunk.
__global__ __launch_bounds__(256) void bin_count_k(
    const int* __restrict__ dst, int* __restrict__ bincnt, int E) {
    __shared__ int hist[NBIN];
    int t = threadIdx.x;
    int base = blockIdx.x * CHUNK;
    int end = min(base + CHUNK, E);
    for (int i = t; i < NBIN; i += 256) hist[i] = 0;
    __syncthreads();
    for (int e = base + t; e < end; e += 256)
        atomicAdd(&hist[dst[e] >> BINSHIFT], 1);
    __syncthreads();
    for (int b = t; b < NBIN; b += 256) {
        int c = hist[b];
        if (c > 0) atomicAdd(&bincnt[b], c);
    }
}

// exclusive scan of bin counts (NBIN <= 512), writes binptr + bincur.
__global__ void binscan_k(const int* __restrict__ bincnt, int* __restrict__ binptr,
                          int* __restrict__ bincur, int nbin, int E) {
    __shared__ int s[512];
    int t = threadIdx.x;
    int v = (t < nbin) ? bincnt[t] : 0;
    s[t] = v;
    __syncthreads();
    for (int off = 1; off < 512; off <<= 1) {
        int tv = (t >= off) ? s[t - off] : 0;
        __syncthreads();
        s[t] += tv;
        __syncthreads();
    }
    if (t < nbin) {
        int excl = s[t] - v;
        binptr[t] = excl;
        bincur[t] = excl;
    }
    if (t == 0) binptr[nbin] = E;
}

// Pass B: scatter edges into dst-range bins. One block per 8192-edge chunk.
// Output word: src | (dst&255)<<24  (src < 2^17 fits in 24 bits).
__global__ __launch_bounds__(256) void bin_edges_k(
    const int* __restrict__ src, const int* __restrict__ dst,
    int* __restrict__ bincur, int* __restrict__ ebuf, int E) {
    __shared__ int hist[NBIN];
    __shared__ int lcur[NBIN];
    int t = threadIdx.x;
    int base = blockIdx.x * CHUNK;
    int end = min(base + CHUNK, E);
    for (int i = t; i < NBIN; i += 256) hist[i] = 0;
    __syncthreads();
    for (int e = base + t; e < end; e += 256)
        atomicAdd(&hist[dst[e] >> BINSHIFT], 1);
    __syncthreads();
    for (int b = t; b < NBIN; b += 256) {
        int c = hist[b];
        lcur[b] = (c > 0) ? atomicAdd(&bincur[b], c) : 0;
    }
    __syncthreads();
    for (int e = base + t; e < end; e += 256) {
        int d = dst[e];
        int bin = d >> BINSHIFT;
        int r = atomicAdd(&lcur[bin], 1);
        ebuf[r] = src[e] | ((d & (BINSIZE - 1)) << 24);
    }
}

// Pass C: one block per bin. LDS degree count -> LDS scan -> rowptr/dinv
// writes -> col scatter with LDS cursors. No global per-node atomics.
__global__ __launch_bounds__(256) void build_csr_k(
    const int* __restrict__ ebuf, const int* __restrict__ binptr,
    int* __restrict__ rowptr, float* __restrict__ dinv,
    int* __restrict__ col, int N, int E, int nbin) {
    __shared__ int lcnt[BINSIZE];
    __shared__ int lscan[BINSIZE];
    __shared__ int lcur[BINSIZE];
    int b = blockIdx.x;
    int t = threadIdx.x;
    int n0 = b << BINSHIFT;
    int e0 = binptr[b];
    int e1 = binptr[b + 1];

    lcnt[t] = 0;
    __syncthreads();
    for (int i = e0 + t; i < e1; i += 256)
        atomicAdd(&lcnt[((unsigned)ebuf[i]) >> 24], 1);
    __syncthreads();

    int v = lcnt[t];
    lscan[t] = v;
    __syncthreads();
    for (int off = 1; off < 256; off <<= 1) {
        int tv = (t >= off) ? lscan[t - off] : 0;
        __syncthreads();
        lscan[t] += tv;
        __syncthreads();
    }
    int excl = e0 + lscan[t] - v;
    lcur[t] = excl;
    if (n0 + t < N) {
        rowptr[n0 + t] = excl;
        dinv[n0 + t] = 1.0f / sqrtf((float)(v + 1));
    }
    if (b == nbin - 1 && t == 0) rowptr[N] = E;
    __syncthreads();

    for (int i = e0 + t; i < e1; i += 256) {
        int w = ebuf[i];
        int dl = ((unsigned)w) >> 24;
        int p = atomicAdd(&lcur[dl], 1);
        col[p] = w & 0xFFFFFF;
    }
}

// ---------------- GEMM + dinv row-scale, chunked output ----------------
// G layout: [8 chunks][N][8 floats]; element (n,j) at ((j>>3)*N + n)*8 + (j&7).
// CHIN: input H also chunked (intermediate layers); else row-major [N][K].
template <int K, bool CHIN>
__global__ __launch_bounds__(256, 4) void gemm_scale_k(
    const float* __restrict__ H, const float* __restrict__ W,
    const float* __restrict__ dinv, float* __restrict__ G, int N) {
    __shared__ float Ws[K * EMB];
    int t = threadIdx.x;
    for (int i = t * 4; i < K * EMB; i += 1024) {
        *(float4*)(Ws + i) = *(const float4*)(W + i);
    }
    __syncthreads();

    int tc = t & 15;   // col group -> 4 cols
    int tr = t >> 4;   // row group -> 4 rows
    int j0 = tc * 4;
    int r0 = blockIdx.x * 64 + tr * 4;
    if (r0 >= N) return;

    int r[4];
#pragma unroll
    for (int i = 0; i < 4; i++) r[i] = (r0 + i < N) ? (r0 + i) : (N - 1);

#define ALOAD(i, k) (CHIN ? *(const float4*)(H + ((size_t)((k) >> 3) * N + r[i]) * 8 + ((k) & 7)) \
                          : *(const float4*)(H + (size_t)r[i] * K + (k)))

    float acc[4][4] = {{0.f}};
    float4 a[4], an[4];
#pragma unroll
    for (int i = 0; i < 4; i++) a[i] = ALOAD(i, 0);

#pragma unroll 1
    for (int k = 0; k < K; k += 4) {
        if (k + 4 < K) {
#pragma unroll
            for (int i = 0; i < 4; i++) an[i] = ALOAD(i, k + 4);
        }
#pragma unroll
        for (int kk = 0; kk < 4; kk++) {
            float4 wv = *(const float4*)(Ws + (k + kk) * EMB + j0);
#pragma unroll
            for (int i = 0; i < 4; i++) {
                float av = (kk == 0) ? a[i].x : (kk == 1) ? a[i].y : (kk == 2) ? a[i].z : a[i].w;
                acc[i][0] = fmaf(av, wv.x, acc[i][0]);
                acc[i][1] = fmaf(av, wv.y, acc[i][1]);
                acc[i][2] = fmaf(av, wv.z, acc[i][2]);
                acc[i][3] = fmaf(av, wv.w, acc[i][3]);
            }
        }
#pragma unroll
        for (int i = 0; i < 4; i++) a[i] = an[i];
    }
#undef ALOAD

#pragma unroll
    for (int i = 0; i < 4; i++) {
        if (r0 + i < N) {
            float s = dinv[r0 + i];
            float4 o = make_float4(acc[i][0] * s, acc[i][1] * s, acc[i][2] * s, acc[i][3] * s);
            *(float4*)(G + ((size_t)(j0 >> 3) * N + (r0 + i)) * 8 + (j0 & 7)) = o;
        }
    }
}

// ---------------- XCD-pinned chunked aggregation ----------------
// Each block reads its physical XCD id and pulls GRAIN-node grains of that
// XCD's chunk from a per-chunk cursor; after its chunk is exhausted it
// steals from the others (correctness never depends on the XCD mapping).
// Wave shape: slot = lane>>3 walks one node's edge list; f = lane&7 is the
// feature. 4 independent gather chains per slot hide L2-hit latency.

__device__ __forceinline__ int get_xcd() {
    int x;
    asm volatile("s_getreg_b32 %0, hwreg(HW_REG_XCC_ID)" : "=s"(x));
    return x & 7;
}

__global__ __launch_bounds__(256) void agg_pin_k(
    const float* __restrict__ G, const float* __restrict__ dinv,
    const int* __restrict__ rowptr, const int* __restrict__ col,
    const float* __restrict__ bias, float* __restrict__ Hout,
    int* __restrict__ cur, int N, int ngrain, int rowmajor_out) {
    int myxcd = get_xcd();
    int wave = threadIdx.x >> 6;
    int lane = threadIdx.x & 63;
    int slot = lane >> 3, f = lane & 7;
    __shared__ int sg;

    for (int off = 0; off < 8; off++) {
        int chunk = (myxcd + off) & 7;
        const float* Gc = G + (size_t)chunk * N * 8;
        float bia = bias[chunk * 8 + f];
        for (;;) {
            __syncthreads();
            if (threadIdx.x == 0) sg = atomicAdd(&cur[chunk], 1);
            __syncthreads();
            int g = sg;
            if (g >= ngrain) break;
            int nw = g * GRAIN + wave * (GRAIN / 4);
#pragma unroll 1
            for (int grp = 0; grp < GRAIN / 32; grp++) {
                int node = nw + grp * 8 + slot;
                if (node >= N) continue;
                int s = rowptr[node], e = rowptr[node + 1];
                float a0 = Gc[(size_t)node * 8 + f];   // self loop
                float a1 = 0.f, a2 = 0.f, a3 = 0.f;
                int i = s;
#pragma unroll 1
                for (; i + 4 <= e; i += 4) {
                    int c0 = col[i], c1 = col[i + 1], c2 = col[i + 2], c3 = col[i + 3];
                    a0 += Gc[(size_t)c0 * 8 + f];
                    a1 += Gc[(size_t)c1 * 8 + f];
                    a2 += Gc[(size_t)c2 * 8 + f];
                    a3 += Gc[(size_t)c3 * 8 + f];
                }
                for (; i < e; i++) a0 += Gc[(size_t)col[i] * 8 + f];
                float v = ((a0 + a1) + (a2 + a3)) * dinv[node] + bia;
                if (rowmajor_out)
                    Hout[(size_t)node * EMB + chunk * 8 + f] = v;
                else
                    Hout[((size_t)chunk * N + node) * 8 + f] = v;
            }
        }
    }
}

// Out = Y @ Wout + bout. Wave per node.
__global__ __launch_bounds__(256) void out_proj_k(
    const float* __restrict__ Y, const float* __restrict__ Wout,
    const float* __restrict__ bout, float* __restrict__ Out, int N) {
    int gw = (blockIdx.x * 256 + threadIdx.x) >> 6;
    int lane = threadIdx.x & 63;
    if (gw >= N) return;
    float p = Y[(size_t)gw * EMB + lane] * Wout[lane];
#pragma unroll
    for (int off = 32; off > 0; off >>= 1) p += __shfl_down(p, off, 64);
    if (lane == 0) Out[gw] = p + bout[0];
}

// ---------------- launch ----------------

extern "C" void kernel_launch(void* const* d_in, const int* in_sizes, int n_in,
                              void* d_out, int out_size, void* d_ws, size_t ws_size,
                              hipStream_t stream) {
    const float* x    = (const float*)d_in[0];
    const int*   ei   = (const int*)d_in[1];
    const float* W0   = (const float*)d_in[3];
    const float* b0   = (const float*)d_in[4];
    const float* W1   = (const float*)d_in[5];
    const float* b1   = (const float*)d_in[6];
    const float* W2   = (const float*)d_in[7];
    const float* b2   = (const float*)d_in[8];
    const float* W3   = (const float*)d_in[9];
    const float* b3   = (const float*)d_in[10];
    const float* Wout = (const float*)d_in[11];
    const float* bout = (const float*)d_in[12];

    const int N = in_sizes[0] / FEAT;      // 100000
    const int E = in_sizes[1] / 2;         // 3200000
    const int* srcp = ei;                  // edge_index[0]
    const int* dstp = ei + E;              // edge_index[1]
    const int nbin = (N + BINSIZE - 1) / BINSIZE;   // 391

    // workspace layout (regions padded to 64 elems for float4 alignment)
    const int NP = ((N + 64) + 63) / 64 * 64;   // holds N+1
    float* dinv  = (float*)d_ws;
    int* rowptr  = (int*)(dinv + NP);
    int* bincnt  = rowptr + NP;            // [0,391) bin counts; [512,512+32) agg cursors
    int* aggcur  = bincnt + 512;           // 4 layers x 8 chunks
    int* binptr  = bincnt + 1024;
    int* bincur  = binptr + 1024;
    int* col     = bincur + 1024;
    float* bufA  = (float*)(col + ((E + 63) / 64) * 64);  // chunked G
    int* ebuf    = (int*)bufA;            // aliased: ebuf dead before first gemm

    float* Out = (float*)d_out;
    float* Y   = Out + N;                 // y-region: chunked mid-layers, row-major at end

    const int gemm_blocks = (N + 63) / 64;
    const int proj_blocks = (N + 3) / 4;
    const int nchunk = (E + CHUNK - 1) / CHUNK;
    const int ngrain = (N + GRAIN - 1) / GRAIN;
    const int agg_blocks = 2048;

    // --- CSR build ---
    zero_k<<<1, 1024, 0, stream>>>(bincnt, 1024);
    bin_count_k<<<nchunk, 256, 0, stream>>>(dstp, bincnt, E);
    binscan_k<<<1, 512, 0, stream>>>(bincnt, binptr, bincur, nbin, E);
    bin_edges_k<<<nchunk, 256, 0, stream>>>(srcp, dstp, bincur, ebuf, E);
    build_csr_k<<<nbin, 256, 0, stream>>>(ebuf, binptr, rowptr, dinv, col, N, E, nbin);

    // --- layer 0 (K=128, row-major in, chunked out) ---
    gemm_scale_k<FEAT, false><<<gemm_blocks, 256, 0, stream>>>(x, W0, dinv, bufA, N);
    agg_pin_k<<<agg_blocks, 256, 0, stream>>>(bufA, dinv, rowptr, col, b0, Y,
                                              aggcur + 0, N, ngrain, 0);
    // --- layer 1 ---
    gemm_scale_k<EMB, true><<<gemm_blocks, 256, 0, stream>>>(Y, W1, dinv, bufA, N);
    agg_pin_k<<<agg_blocks, 256, 0, stream>>>(bufA, dinv, rowptr, col, b1, Y,
                                              aggcur + 8, N, ngrain, 0);
    // --- layer 2 ---
    gemm_scale_k<EMB, true><<<gemm_blocks, 256, 0, stream>>>(Y, W2, dinv, bufA, N);
    agg_pin_k<<<agg_blocks, 256, 0, stream>>>(bufA, dinv, rowptr, col, b2, Y,
                                              aggcur + 16, N, ngrain, 0);
    // --- layer 3: row-major Y out + projection ---
    gemm_scale_k<EMB, true><<<gemm_blocks, 256, 0, stream>>>(Y, W3, dinv, bufA, N);
    agg_pin_k<<<agg_blocks, 256, 0, stream>>>(bufA, dinv, rowptr, col, b3, Y,
                                              aggcur + 24, N, ngrain, 1);
    out_proj_k<<<proj_blocks, 256, 0, stream>>>(Y, Wout, bout, Out, N);
}

// Round 9
// 759.433 us; speedup vs baseline: 2.3627x; 2.3627x over previous
//
#include <hip/hip_runtime.h>

// ---------------------------------------------------------------------------
// GCN: 4 layers of  h' = A_hat_norm (h @ W) + b   on fixed graph, fp32.
// deg[i] = in_degree(i) + 1 (self loop), dinv = 1/sqrt(deg),
// g = (h@W) * dinv[row]  (GEMM epilogue), then per-dst:
//   h'[dst] = dinv[dst] * ( g[dst] + sum_{src in N(dst)} g[src] ) + b
// R2: gemm spill fixed (unroll 1 + manual pipeline).
// R3: CSR fill via binned counting sort (L2-merged scatters).
// R4: per-node degree/scan/fill in LDS per 256-node bin. (784us, best)
// R5-R8: feature-chunked G + XCD pinning experiments -- chunk residency
// never held under long-lived blocks (FETCH bounced back to 257MB) and
// latency suffered; REVERTED to R4 structure.
// R9: R4 + agg gather loop unrolled to 8 independent chains (8 outstanding
// 256B row-gathers per wave vs 4) to close the latency-hiding gap
// (R4 agg: 3.3TB/s, VALUBusy 24%).
// ---------------------------------------------------------------------------

#define FEAT 128
#define EMB 64
#define BINSHIFT 8
#define BINSIZE 256
#define NBIN 391          // ceil(100000/256)
#define CHUNK 8192

// ---------------- CSR build ----------------

__global__ void zero_k(int* __restrict__ p, int n) {
    int i = blockIdx.x * blockDim.x + threadIdx.x;
    if (i < n) p[i] = 0;
}

// Pass A: per-bin edge counts. LDS histogram per chunk.
__global__ __launch_bounds__(256) void bin_count_k(
    const int* __restrict__ dst, int* __restrict__ bincnt, int E) {
    __shared__ int hist[NBIN];
    int t = threadIdx.x;
    int base = blockIdx.x * CHUNK;
    int end = min(base + CHUNK, E);
    for (int i = t; i < NBIN; i += 256) hist[i] = 0;
    __syncthreads();
    for (int e = base + t; e < end; e += 256)
        atomicAdd(&hist[dst[e] >> BINSHIFT], 1);
    __syncthreads();
    for (int b = t; b < NBIN; b += 256) {
        int c = hist[b];
        if (c > 0) atomicAdd(&bincnt[b], c);
    }
}

// exclusive scan of bin counts (NBIN <= 512), writes binptr + bincur.
__global__ void binscan_k(const int* __restrict__ bincnt, int* __restrict__ binptr,
                          int* __restrict__ bincur, int nbin, int E) {
    __shared__ int s[512];
    int t = threadIdx.x;
    int v = (t < nbin) ? bincnt[t] : 0;
    s[t] = v;
    __syncthreads();
    for (int off = 1; off < 512; off <<= 1) {
        int tv = (t >= off) ? s[t - off] : 0;
        __syncthreads();
        s[t] += tv;
        __syncthreads();
    }
    if (t < nbin) {
        int excl = s[t] - v;
        binptr[t] = excl;
        bincur[t] = excl;
    }
    if (t == 0) binptr[nbin] = E;
}

// Pass B: scatter edges into dst-range bins. One block per 8192-edge chunk.
// Output word: src | (dst&255)<<24  (src < 2^17 fits in 24 bits).
__global__ __launch_bounds__(256) void bin_edges_k(
    const int* __restrict__ src, const int* __restrict__ dst,
    int* __restrict__ bincur, int* __restrict__ ebuf, int E) {
    __shared__ int hist[NBIN];
    __shared__ int lcur[NBIN];
    int t = threadIdx.x;
    int base = blockIdx.x * CHUNK;
    int end = min(base + CHUNK, E);
    for (int i = t; i < NBIN; i += 256) hist[i] = 0;
    __syncthreads();
    for (int e = base + t; e < end; e += 256)
        atomicAdd(&hist[dst[e] >> BINSHIFT], 1);
    __syncthreads();
    for (int b = t; b < NBIN; b += 256) {
        int c = hist[b];
        lcur[b] = (c > 0) ? atomicAdd(&bincur[b], c) : 0;
    }
    __syncthreads();
    for (int e = base + t; e < end; e += 256) {
        int d = dst[e];
        int bin = d >> BINSHIFT;
        int r = atomicAdd(&lcur[bin], 1);
        ebuf[r] = src[e] | ((d & (BINSIZE - 1)) << 24);
    }
}

// Pass C: one block per bin. LDS degree count -> LDS scan -> rowptr/dinv
// writes -> col scatter with LDS cursors. No global per-node atomics.
__global__ __launch_bounds__(256) void build_csr_k(
    const int* __restrict__ ebuf, const int* __restrict__ binptr,
    int* __restrict__ rowptr, float* __restrict__ dinv,
    int* __restrict__ col, int N, int E, int nbin) {
    __shared__ int lcnt[BINSIZE];
    __shared__ int lscan[BINSIZE];
    __shared__ int lcur[BINSIZE];
    int b = blockIdx.x;
    int t = threadIdx.x;
    int n0 = b << BINSHIFT;
    int e0 = binptr[b];
    int e1 = binptr[b + 1];

    lcnt[t] = 0;
    __syncthreads();
    for (int i = e0 + t; i < e1; i += 256)
        atomicAdd(&lcnt[((unsigned)ebuf[i]) >> 24], 1);
    __syncthreads();

    int v = lcnt[t];
    lscan[t] = v;
    __syncthreads();
    for (int off = 1; off < 256; off <<= 1) {
        int tv = (t >= off) ? lscan[t - off] : 0;
        __syncthreads();
        lscan[t] += tv;
        __syncthreads();
    }
    int excl = e0 + lscan[t] - v;
    lcur[t] = excl;
    if (n0 + t < N) {
        rowptr[n0 + t] = excl;
        dinv[n0 + t] = 1.0f / sqrtf((float)(v + 1));
    }
    if (b == nbin - 1 && t == 0) rowptr[N] = E;
    __syncthreads();

    for (int i = e0 + t; i < e1; i += 256) {
        int w = ebuf[i];
        int dl = ((unsigned)w) >> 24;
        int p = atomicAdd(&lcur[dl], 1);
        col[p] = w & 0xFFFFFF;
    }
}

// ---------------- GEMM + dinv row-scale:  G = (H @ W) * dinv[row] ----------------
// Block: 256 threads -> 64 rows x 64 cols, each thread 4x4 outputs.
// Manual 1-deep pipeline on the A loads; unroll 1 keeps VGPR < 128.
template <int K>
__global__ __launch_bounds__(256, 4) void gemm_scale_k(
    const float* __restrict__ H, const float* __restrict__ W,
    const float* __restrict__ dinv, float* __restrict__ G, int N) {
    __shared__ float Ws[K * EMB];
    int t = threadIdx.x;
    for (int i = t * 4; i < K * EMB; i += 1024) {
        *(float4*)(Ws + i) = *(const float4*)(W + i);
    }
    __syncthreads();

    int tc = t & 15;   // col group -> 4 cols
    int tr = t >> 4;   // row group -> 4 rows
    int j0 = tc * 4;
    int r0 = blockIdx.x * 64 + tr * 4;
    if (r0 >= N) return;

    const float* hp[4];
#pragma unroll
    for (int i = 0; i < 4; i++) {
        int r = (r0 + i < N) ? (r0 + i) : (N - 1);
        hp[i] = H + (size_t)r * K;
    }

    float acc[4][4] = {{0.f}};
    float4 a[4], an[4];
#pragma unroll
    for (int i = 0; i < 4; i++) a[i] = *(const float4*)(hp[i]);

#pragma unroll 1
    for (int k = 0; k < K; k += 4) {
        if (k + 4 < K) {
#pragma unroll
            for (int i = 0; i < 4; i++) an[i] = *(const float4*)(hp[i] + k + 4);
        }
#pragma unroll
        for (int kk = 0; kk < 4; kk++) {
            float4 wv = *(const float4*)(Ws + (k + kk) * EMB + j0);
#pragma unroll
            for (int i = 0; i < 4; i++) {
                float av = (kk == 0) ? a[i].x : (kk == 1) ? a[i].y : (kk == 2) ? a[i].z : a[i].w;
                acc[i][0] = fmaf(av, wv.x, acc[i][0]);
                acc[i][1] = fmaf(av, wv.y, acc[i][1]);
                acc[i][2] = fmaf(av, wv.z, acc[i][2]);
                acc[i][3] = fmaf(av, wv.w, acc[i][3]);
            }
        }
#pragma unroll
        for (int i = 0; i < 4; i++) a[i] = an[i];
    }

#pragma unroll
    for (int i = 0; i < 4; i++) {
        if (r0 + i < N) {
            float s = dinv[r0 + i];
            float4 o = make_float4(acc[i][0] * s, acc[i][1] * s, acc[i][2] * s, acc[i][3] * s);
            *(float4*)(G + (size_t)(r0 + i) * EMB + j0) = o;
        }
    }
}

// ---------------- Aggregation: one wave per node, one lane per feature ----------------
// 8 independent gather chains per wave: 8 outstanding 256B row-gathers
// before the first dependent add -> hides L2/L3/HBM latency better than
// R4's 4-deep version (which sustained only 3.3 TB/s at VALUBusy 24%).

__device__ __forceinline__ float agg_node(const float* __restrict__ G,
                                          const int* __restrict__ col,
                                          int s, int e, int node, int lane) {
    float a0 = G[(size_t)node * EMB + lane];  // self loop
    float a1 = 0.f, a2 = 0.f, a3 = 0.f;
    float a4 = 0.f, a5 = 0.f, a6 = 0.f, a7 = 0.f;
    int i = s;
    for (; i + 8 <= e; i += 8) {
        int s0 = __builtin_amdgcn_readfirstlane(col[i]);
        int s1 = __builtin_amdgcn_readfirstlane(col[i + 1]);
        int s2 = __builtin_amdgcn_readfirstlane(col[i + 2]);
        int s3 = __builtin_amdgcn_readfirstlane(col[i + 3]);
        int s4 = __builtin_amdgcn_readfirstlane(col[i + 4]);
        int s5 = __builtin_amdgcn_readfirstlane(col[i + 5]);
        int s6 = __builtin_amdgcn_readfirstlane(col[i + 6]);
        int s7 = __builtin_amdgcn_readfirstlane(col[i + 7]);
        float g0 = G[(size_t)s0 * EMB + lane];
        float g1 = G[(size_t)s1 * EMB + lane];
        float g2 = G[(size_t)s2 * EMB + lane];
        float g3 = G[(size_t)s3 * EMB + lane];
        float g4 = G[(size_t)s4 * EMB + lane];
        float g5 = G[(size_t)s5 * EMB + lane];
        float g6 = G[(size_t)s6 * EMB + lane];
        float g7 = G[(size_t)s7 * EMB + lane];
        a0 += g0; a1 += g1; a2 += g2; a3 += g3;
        a4 += g4; a5 += g5; a6 += g6; a7 += g7;
    }
    for (; i + 2 <= e; i += 2) {
        int s0 = __builtin_amdgcn_readfirstlane(col[i]);
        int s1 = __builtin_amdgcn_readfirstlane(col[i + 1]);
        a0 += G[(size_t)s0 * EMB + lane];
        a1 += G[(size_t)s1 * EMB + lane];
    }
    if (i < e) {
        int s0 = __builtin_amdgcn_readfirstlane(col[i]);
        a2 += G[(size_t)s0 * EMB + lane];
    }
    return ((a0 + a1) + (a2 + a3)) + ((a4 + a5) + (a6 + a7));
}

__global__ __launch_bounds__(256) void agg_k(
    const float* __restrict__ G, const float* __restrict__ dinv,
    const int* __restrict__ rowptr, const int* __restrict__ col,
    const float* __restrict__ bias, float* __restrict__ Hout, int N) {
    int gw = (blockIdx.x * 256 + threadIdx.x) >> 6;
    int lane = threadIdx.x & 63;
    if (gw >= N) return;
    int s = rowptr[gw], e = rowptr[gw + 1];
    float acc = agg_node(G, col, s, e, gw, lane);
    Hout[(size_t)gw * EMB + lane] = acc * dinv[gw] + bias[lane];
}

// Final layer: also project y @ Wout + bout into Out.
__global__ __launch_bounds__(256) void agg_final_k(
    const float* __restrict__ G, const float* __restrict__ dinv,
    const int* __restrict__ rowptr, const int* __restrict__ col,
    const float* __restrict__ bias, const float* __restrict__ Wout,
    const float* __restrict__ bout, float* __restrict__ Y,
    float* __restrict__ Out, int N) {
    int gw = (blockIdx.x * 256 + threadIdx.x) >> 6;
    int lane = threadIdx.x & 63;
    if (gw >= N) return;
    int s = rowptr[gw], e = rowptr[gw + 1];
    float acc = agg_node(G, col, s, e, gw, lane);
    float val = acc * dinv[gw] + bias[lane];
    Y[(size_t)gw * EMB + lane] = val;
    float p = val * Wout[lane];
#pragma unroll
    for (int off = 32; off > 0; off >>= 1) p += __shfl_down(p, off, 64);
    if (lane == 0) Out[gw] = p + bout[0];
}

// ---------------- launch ----------------

extern "C" void kernel_launch(void* const* d_in, const int* in_sizes, int n_in,
                              void* d_out, int out_size, void* d_ws, size_t ws_size,
                              hipStream_t stream) {
    const float* x    = (const float*)d_in[0];
    const int*   ei   = (const int*)d_in[1];
    const float* W0   = (const float*)d_in[3];
    const float* b0   = (const float*)d_in[4];
    const float* W1   = (const float*)d_in[5];
    const float* b1   = (const float*)d_in[6];
    const float* W2   = (const float*)d_in[7];
    const float* b2   = (const float*)d_in[8];
    const float* W3   = (const float*)d_in[9];
    const float* b3   = (const float*)d_in[10];
    const float* Wout = (const float*)d_in[11];
    const float* bout = (const float*)d_in[12];

    const int N = in_sizes[0] / FEAT;      // 100000
    const int E = in_sizes[1] / 2;         // 3200000
    const int* srcp = ei;                  // edge_index[0]
    const int* dstp = ei + E;              // edge_index[1]
    const int nbin = (N + BINSIZE - 1) / BINSIZE;   // 391

    // workspace layout (regions padded to 64 elems for float4 alignment)
    const int NP = ((N + 64) + 63) / 64 * 64;   // holds N+1
    float* dinv  = (float*)d_ws;
    int* rowptr  = (int*)(dinv + NP);
    int* bincnt  = rowptr + NP;
    int* binptr  = bincnt + 1024;
    int* bincur  = binptr + 1024;
    int* col     = bincur + 1024;
    float* bufA  = (float*)(col + ((E + 63) / 64) * 64);
    int* ebuf    = (int*)bufA;            // aliased: ebuf dead before first gemm

    float* Out = (float*)d_out;
    float* Y   = Out + N;                 // reuse y-region of d_out as ping-pong buffer

    const int gemm_blocks = (N + 63) / 64;
    const int agg_blocks  = (N + 3) / 4;
    const int nchunk = (E + CHUNK - 1) / CHUNK;

    // --- CSR build ---
    zero_k<<<1, 1024, 0, stream>>>(bincnt, 1024);
    bin_count_k<<<nchunk, 256, 0, stream>>>(dstp, bincnt, E);
    binscan_k<<<1, 512, 0, stream>>>(bincnt, binptr, bincur, nbin, E);
    bin_edges_k<<<nchunk, 256, 0, stream>>>(srcp, dstp, bincur, ebuf, E);
    build_csr_k<<<nbin, 256, 0, stream>>>(ebuf, binptr, rowptr, dinv, col, N, E, nbin);

    // --- layer 0 (K=128) ---
    gemm_scale_k<FEAT><<<gemm_blocks, 256, 0, stream>>>(x, W0, dinv, bufA, N);
    agg_k<<<agg_blocks, 256, 0, stream>>>(bufA, dinv, rowptr, col, b0, Y, N);
    // --- layer 1 ---
    gemm_scale_k<EMB><<<gemm_blocks, 256, 0, stream>>>(Y, W1, dinv, bufA, N);
    agg_k<<<agg_blocks, 256, 0, stream>>>(bufA, dinv, rowptr, col, b1, Y, N);
    // --- layer 2 ---
    gemm_scale_k<EMB><<<gemm_blocks, 256, 0, stream>>>(Y, W2, dinv, bufA, N);
    agg_k<<<agg_blocks, 256, 0, stream>>>(bufA, dinv, rowptr, col, b2, Y, N);
    // --- layer 3 + output projection ---
    gemm_scale_k<EMB><<<gemm_blocks, 256, 0, stream>>>(Y, W3, dinv, bufA, N);
    agg_final_k<<<agg_blocks, 256, 0, stream>>>(bufA, dinv, rowptr, col, b3, Wout, bout,
                                                Y, Out, N);
}